// Round 6
// baseline (240.662 us; speedup 1.0000x reference)
//
#include <hip/hip_runtime.h>

// LinearLIFBlock: cur = X[16384x1024] * W^T[1024x1024]; LIF scan over t (64 steps).
// R15: fuse X bf16-split into gemm A-staging (kill the 192 MB A-buffer round
// trip; R14 proved split micro-opt doesn't move the wall; non-gemm floor
// ~120us). A-staging is now reg-staged (T14 issue-early/write-late): per
// half-iteration {4x global_load_dwordx4 f32 X -> COMPUTE hides latency ->
// RNE-convert to hi/lo bf16 (identical math -> bit-identical LDS bytes ->
// cur bit-identical -> same fixup set) -> 4x ds_write_b128 -> HARD_SYNC}.
// Same dbuf barrier discipline as R12 (writes precede the buffer's HARD_SYNC;
// lgkmcnt(0) covers ds_writes). R13 lesson respected: only 16 f32 temps cross
// one sched_barrier(0); all short8 fragments stay inside fence-free regions.
// B (W-side) staging unchanged via global_load_lds from a tiny packed buffer
// produced by split_w (512 blocks, 4 MB). Workspace 68 MB -> 4.3 MB.
// Geometry (256x256, wave 128x64, grid 256), XOR swizzle, LIF relay, margin
// 6e-5 + exact fp64 fixup unchanged.

#define T_DIM 64
#define B_DIM 256
#define F_DIM 1024
#define K_DIM 1024
#define M_DIM 16384            // T*B
#define COLS  (B_DIM * F_DIM)  // 262144 scan columns
#define KP    2048             // packed K: [hi | lo]
#define MARGIN 6e-5f
#define LIST_CAP 32768

typedef __attribute__((ext_vector_type(8))) short short8;
typedef __attribute__((ext_vector_type(4))) float floatx4;

#define ASYNC_CP16(gp, lp)                                                     \
    __builtin_amdgcn_global_load_lds(                                          \
        (const __attribute__((address_space(1))) unsigned int*)(gp),           \
        (__attribute__((address_space(3))) unsigned int*)(lp), 16, 0, 0)

// Hardened pipeline sync: explicit full drain + pinned ordering (R12-validated).
#define HARD_SYNC() do {                                                       \
        __builtin_amdgcn_sched_barrier(0);                                     \
        asm volatile("s_waitcnt vmcnt(0) lgkmcnt(0)" ::: "memory");            \
        __syncthreads();                                                       \
        __builtin_amdgcn_sched_barrier(0);                                     \
    } while (0)

// ---------------------------------------------------------------- bf16 split
__device__ inline unsigned short f32_to_bf16_rne(float f) {
    unsigned int u = __builtin_bit_cast(unsigned int, f);
    unsigned int r = (u + 0x7FFFu + ((u >> 16) & 1u)) >> 16;
    return (unsigned short)r;
}
__device__ inline float bf16_to_f32(unsigned short h) {
    unsigned int u = ((unsigned int)h) << 16;
    return __builtin_bit_cast(float, u);
}

// W-only split: 512 blocks x 256 threads x 8 floats = 1M floats (whole W).
// Per-element conversion identical to R12/R14 -> bit-identical B buffer.
// Also zeroes the fixup counter (blk 0).
__global__ __launch_bounds__(256) void split_w_kernel(
    const float* __restrict__ Wm, unsigned short* __restrict__ B,
    unsigned int* __restrict__ counter)
{
    if (blockIdx.x == 0 && threadIdx.x == 0) *counter = 0;
    const int g2 = blockIdx.x * 256 + threadIdx.x;   // float8-group index
    const int e = g2 * 8;
    const int orow = e >> 10;                        // o
    const int k = e & 1023;
    float4 v0 = reinterpret_cast<const float4*>(Wm)[g2 * 2];
    float4 v1 = reinterpret_cast<const float4*>(Wm)[g2 * 2 + 1];
    float fs[8] = {v0.x, v0.y, v0.z, v0.w, v1.x, v1.y, v1.z, v1.w};
    short8 hv, lv;
#pragma unroll
    for (int i = 0; i < 8; ++i) {
        unsigned short h = f32_to_bf16_rne(fs[i]);
        unsigned short l = f32_to_bf16_rne(fs[i] - bf16_to_f32(h));
        hv[i] = (short)h;
        lv[i] = (short)l;
    }
    reinterpret_cast<short8*>(B)[(size_t)orow * (KP / 8) + (k >> 3)] = hv;
    reinterpret_cast<short8*>(B)[(size_t)orow * (KP / 8) + 128 + (k >> 3)] = lv;
}

// ----------------------------------------------- fused MFMA GEMM + LIF scan
// Block tile 256(M) x 256(N); 512 threads (8 waves, 2M x 4N), wave 128x64.
// A staged from raw f32 X (reg-staged + on-the-fly hi/lo split); B staged
// from packed buffer via global_load_lds. 2-phase dbuf, one hardened barrier
// per k-tile.  cur = A.hi*B.hi + A.lo*B.hi + A.hi*B.lo
__global__ __launch_bounds__(512, 2) void gemm_scan_kernel(
    const float* __restrict__ x,           // [64][256][1024] f32
    const unsigned short* __restrict__ B,  // [1024][2048] packed hi|lo, rows o
    float* __restrict__ out,
    unsigned int* __restrict__ counter, unsigned int* __restrict__ list)
{
    __shared__ unsigned short Ah0[256 * 32], Al0[256 * 32];  // 32 KB
    __shared__ unsigned short Bh0[256 * 32], Bl0[256 * 32];  // 32 KB
    __shared__ unsigned short Ah1[256 * 32], Al1[256 * 32];  // 32 KB
    __shared__ unsigned short Bh1[256 * 32], Bl1[256 * 32];  // 32 KB

    const int tid  = threadIdx.x;
    const int lane = tid & 63;
    const int wv   = tid >> 6;                       // 0..7
    // XCD-aware: XCD = lid&7 owns 8 mt x 4 nt contiguous blocks.
    const int lid = blockIdx.x;                      // 0..255
    const int mt  = ((lid & 7) << 3) | (lid >> 5);   // 0..63
    const int nt  = (lid >> 3) & 3;                  // 0..3
    const int m0  = mt * 256;
    const int n0  = nt * 256;
    const int wm  = (wv & 1) * 128;
    const int wn  = (wv >> 1) * 64;

    floatx4 acc[8][4] = {};

    // Staging with source-side XOR chunk swizzle (R5/R7-validated: 0 conflicts).
    const int srow = tid >> 2;                      // 0..127 staging row
    const int slin = (tid & 3) * 8;                 // linear LDS chunk (dest)
    const int ssw  = (((tid & 3) ^ ((srow >> 1) & 3)) * 8);  // swizzled source chunk
    const int lrow = lane & 15;
    const int q    = lane >> 4;                     // 0..3
    const int rsw  = (lrow >> 1) & 3;               // read-side swizzle key
    const int sl   = (q ^ rsw) * 8;

    // A source: rows of the logical packed-A matrix map back to x:
    //   A-row ar = b*64 + t  <->  x-row = t*256 + b   (b = ar>>6, t = ar&63)
    const int ar0 = m0 + srow;
    const int ar1 = ar0 + 128;
    const float* xr0 =
        x + ((size_t)(ar0 & 63) * 256 + (ar0 >> 6)) * 1024 + ssw;
    const float* xr1 =
        x + ((size_t)(ar1 & 63) * 256 + (ar1 >> 6)) * 1024 + ssw;

    // B source (packed, pre-swizzled); rows srow and srow+128
    const size_t RKP = (size_t)128 * KP;
    const unsigned short* gb_h = B + (size_t)(n0 + srow) * KP + ssw;
    const unsigned short* gb_l = gb_h + 1024;

    // LDS dest offsets (lane-linear within each wave: lane -> base + lane*16B)
    const int ldsA  = srow * 32 + slin;
    const int ldsA2 = (srow + 128) * 32 + slin;

    // fragment read offsets
    int aoff[8], boff[4];
#pragma unroll
    for (int i = 0; i < 8; ++i) aoff[i] = (wm + i * 16 + lrow) * 32 + sl;
#pragma unroll
    for (int j = 0; j < 4; ++j) boff[j] = (wn + j * 16 + lrow) * 32 + sl;

    // f32 staging temps (live across COMPUTE; die before HARD_SYNC)
    float4 fA0, fA0b, fA1, fA1b;

#define STAGE_A_LOAD(kk) do {                                                  \
        fA0  = *reinterpret_cast<const float4*>(xr0 + (kk));                   \
        fA0b = *reinterpret_cast<const float4*>(xr0 + (kk) + 4);               \
        fA1  = *reinterpret_cast<const float4*>(xr1 + (kk));                   \
        fA1b = *reinterpret_cast<const float4*>(xr1 + (kk) + 4);               \
    } while (0)

#define STAGE_B(BhB, BlB, kk) do {                                             \
        ASYNC_CP16(gb_h + (kk),       &BhB[ldsA]);                             \
        ASYNC_CP16(gb_h + RKP + (kk), &BhB[ldsA2]);                            \
        ASYNC_CP16(gb_l + (kk),       &BlB[ldsA]);                             \
        ASYNC_CP16(gb_l + RKP + (kk), &BlB[ldsA2]);                            \
    } while (0)

// Convert 8 f32 -> hi/lo bf16 short8 and store to LDS. RNE math identical to
// the split kernel -> bit-identical LDS bytes.
#define CVT8(dsth, dstl, va, vb) do {                                          \
        float fs[8] = {va.x, va.y, va.z, va.w, vb.x, vb.y, vb.z, vb.w};        \
        short8 hv, lv;                                                         \
        _Pragma("unroll")                                                      \
        for (int ii = 0; ii < 8; ++ii) {                                       \
            unsigned short h = f32_to_bf16_rne(fs[ii]);                        \
            unsigned short l = f32_to_bf16_rne(fs[ii] - bf16_to_f32(h));       \
            hv[ii] = (short)h;                                                 \
            lv[ii] = (short)l;                                                 \
        }                                                                      \
        *reinterpret_cast<short8*>(dsth) = hv;                                 \
        *reinterpret_cast<short8*>(dstl) = lv;                                 \
    } while (0)

#define CVT_WRITE(AhB, AlB) do {                                               \
        CVT8(&AhB[ldsA],  &AlB[ldsA],  fA0, fA0b);                             \
        CVT8(&AhB[ldsA2], &AlB[ldsA2], fA1, fA1b);                             \
    } while (0)

#define COMPUTE(AhB, AlB, BhB, BlB) do {                                       \
        short8 ah[8], al[8];                                                   \
        _Pragma("unroll")                                                      \
        for (int i = 0; i < 8; ++i) {                                          \
            ah[i] = *reinterpret_cast<const short8*>(&AhB[aoff[i]]);           \
            al[i] = *reinterpret_cast<const short8*>(&AlB[aoff[i]]);           \
        }                                                                      \
        _Pragma("unroll")                                                      \
        for (int jh = 0; jh < 2; ++jh) {                                       \
            short8 bh[2], bl[2];                                               \
            _Pragma("unroll")                                                  \
            for (int j2 = 0; j2 < 2; ++j2) {                                   \
                bh[j2] = *reinterpret_cast<const short8*>(&BhB[boff[jh * 2 + j2]]); \
                bl[j2] = *reinterpret_cast<const short8*>(&BlB[boff[jh * 2 + j2]]); \
            }                                                                  \
            __builtin_amdgcn_s_setprio(1);                                     \
            _Pragma("unroll")                                                  \
            for (int i = 0; i < 8; ++i)                                        \
                _Pragma("unroll")                                              \
                for (int j2 = 0; j2 < 2; ++j2)                                 \
                    acc[i][jh * 2 + j2] = __builtin_amdgcn_mfma_f32_16x16x32_bf16( \
                        ah[i], bh[j2], acc[i][jh * 2 + j2], 0, 0, 0);          \
            _Pragma("unroll")                                                  \
            for (int i = 0; i < 8; ++i)                                        \
                _Pragma("unroll")                                              \
                for (int j2 = 0; j2 < 2; ++j2)                                 \
                    acc[i][jh * 2 + j2] = __builtin_amdgcn_mfma_f32_16x16x32_bf16( \
                        al[i], bh[j2], acc[i][jh * 2 + j2], 0, 0, 0);          \
            _Pragma("unroll")                                                  \
            for (int i = 0; i < 8; ++i)                                        \
                _Pragma("unroll")                                              \
                for (int j2 = 0; j2 < 2; ++j2)                                 \
                    acc[i][jh * 2 + j2] = __builtin_amdgcn_mfma_f32_16x16x32_bf16( \
                        ah[i], bl[j2], acc[i][jh * 2 + j2], 0, 0, 0);          \
            __builtin_amdgcn_s_setprio(0);                                     \
        }                                                                      \
    } while (0)

    // prologue: fill buf0 for k-tile 0 (A: load -> cvt -> ds_write; B: gload_lds)
    STAGE_A_LOAD(0);
    STAGE_B(Bh0, Bl0, 0);
    CVT_WRITE(Ah0, Al0);
    HARD_SYNC();   // buf0 ready (vmcnt(0) drains B; lgkmcnt(0) drains A writes)

#pragma unroll 1
    for (int kt = 0; kt < 32; kt += 2) {
        // phase A: compute tile kt from buf0; prep tile kt+1 into buf1
        STAGE_A_LOAD((kt + 1) * 32);
        STAGE_B(Bh1, Bl1, (kt + 1) * 32);
        __builtin_amdgcn_sched_barrier(0);   // loads stay issued before MFMA
        COMPUTE(Ah0, Al0, Bh0, Bl0);
        __builtin_amdgcn_sched_barrier(0);   // cvt stays after MFMA (T14 write-late)
        CVT_WRITE(Ah1, Al1);
        HARD_SYNC();   // buf1 ready; buf0 free to overwrite
        // phase B: compute tile kt+1 from buf1; prep tile kt+2 into buf0
        if (kt + 2 < 32) {
            STAGE_A_LOAD((kt + 2) * 32);
            STAGE_B(Bh0, Bl0, (kt + 2) * 32);
        }
        __builtin_amdgcn_sched_barrier(0);
        COMPUTE(Ah1, Al1, Bh1, Bl1);
        __builtin_amdgcn_sched_barrier(0);
        if (kt + 2 < 32) CVT_WRITE(Ah0, Al0);
        HARD_SYNC();
    }

#undef STAGE_A_LOAD
#undef STAGE_B
#undef CVT8
#undef CVT_WRITE
#undef COMPUTE

    // ---- fused LIF scan in registers (validated relay, 2 batches/wave) ----
    // Wave rows wm..wm+127 = batches b_base, b_base+1 (64 t each).
    // acc[i][j][r] = cur at batch b_base+(i>>2), t = (i&3)*16 + q*4 + r,
    // col o = n0 + wn + j*16 + (lane&15).
    const int col = lane & 15;
    const int b_base = mt * 4 + (wv & 1) * 2;

    unsigned int fmask = 0;
#pragma unroll
    for (int hb = 0; hb < 2; ++hb) {
#pragma unroll
        for (int j = 0; j < 4; ++j) {
            float v = 0.f;
            bool fl = false;
#pragma unroll
            for (int i4 = 0; i4 < 4; ++i4) {
                const int i = hb * 4 + i4;
#pragma unroll
                for (int qq = 0; qq < 4; ++qq) {
                    if (q == qq) {
#pragma unroll
                        for (int r = 0; r < 4; ++r) {
                            float cu = acc[i][j][r];
                            float hm = v + (cu - v) * 0.5f;
                            float d = hm - 1.0f;
                            bool sp = (d >= 0.f);
                            fl |= (fabsf(d) < MARGIN);
                            acc[i][j][r] = sp ? 1.0f : 0.0f;  // spike overwrites cur
                            v = sp ? 0.f : hm;
                        }
                    }
                    v = __shfl(v, qq * 16 + col, 64);  // broadcast owner's v
                }
            }
            if (fl) fmask |= (1u << (hb * 4 + j));
        }
    }
    fmask |= __shfl_xor(fmask, 16, 64);
    fmask |= __shfl_xor(fmask, 32, 64);

    // spike stores
#pragma unroll
    for (int i = 0; i < 8; ++i) {
        float* outp = out + (size_t)(b_base + (i >> 2)) * F_DIM;
        const int tb = (i & 3) * 16 + q * 4;
#pragma unroll
        for (int j = 0; j < 4; ++j)
#pragma unroll
            for (int r = 0; r < 4; ++r)
                outp[(size_t)(tb + r) * COLS + (n0 + wn + j * 16 + col)] = acc[i][j][r];
    }

    if (q == 0 && fmask) {
        for (int hb = 0; hb < 2; ++hb)
            for (int j = 0; j < 4; ++j)
                if (fmask & (1u << (hb * 4 + j))) {
                    unsigned int idx = atomicAdd(counter, 1u);
                    if (idx < LIST_CAP)
                        list[idx] = (unsigned int)(((b_base + hb) << 10) |
                                                   (n0 + wn + j * 16 + col));
                }
    }
}

// ------------------------------------------------------- exact fp64 fixup
__global__ __launch_bounds__(256) void fixup_kernel(
    const float* __restrict__ x, const float* __restrict__ W,
    const unsigned int* __restrict__ counter, const unsigned int* __restrict__ list,
    float* __restrict__ out)
{
    __shared__ double curd[T_DIM];
    __shared__ float wrow[K_DIM];
    unsigned int n = *counter;
    if (n > LIST_CAP) n = LIST_CAP;
    const int wv = threadIdx.x >> 6, lane = threadIdx.x & 63;

    for (unsigned int idx = blockIdx.x; idx < n; idx += gridDim.x) {
        const unsigned int c = list[idx];
        const int b = c >> 10, o = c & 1023;
        __syncthreads();
        for (int k = threadIdx.x; k < K_DIM; k += 256) wrow[k] = W[(size_t)o * K_DIM + k];
        __syncthreads();
        for (int it = 0; it < 16; ++it) {
            const int t = it * 4 + wv;
            const float* xp = x + (size_t)t * COLS + (size_t)b * F_DIM + lane * 16;
            double s = 0.0;
#pragma unroll
            for (int qq = 0; qq < 4; ++qq) {
                float4 xv = reinterpret_cast<const float4*>(xp)[qq];
                float4 wq = *reinterpret_cast<const float4*>(&wrow[lane * 16 + qq * 4]);
                s += (double)xv.x * (double)wq.x + (double)xv.y * (double)wq.y +
                     (double)xv.z * (double)wq.z + (double)xv.w * (double)wq.w;
            }
#pragma unroll
            for (int off = 32; off > 0; off >>= 1) s += __shfl_down(s, off, 64);
            if (lane == 0) curd[t] = s;
        }
        __syncthreads();
        if (threadIdx.x == 0) {
            double v = 0.0;
            for (int t = 0; t < T_DIM; ++t) {
                double h = v + (curd[t] - v) * 0.5;
                bool s = (h >= 1.0);
                out[(size_t)t * COLS + c] = s ? 1.0f : 0.0f;
                v = s ? 0.0 : h;
            }
        }
        __syncthreads();
    }
}

// --------------------------------------------------- fp64 fallback (round-1)
#define TILE 64
#define KC 32
#define XS_LD 36
#define SC_LD 65

__global__ __launch_bounds__(256) void lif_fused_kernel(
    const float* __restrict__ x, const float* __restrict__ Wm, float* __restrict__ out)
{
    __shared__ __align__(16) unsigned char smem_raw[TILE * SC_LD * sizeof(double)];
    float* sf = reinterpret_cast<float*>(smem_raw);
    double* sd = reinterpret_cast<double*>(smem_raw);
    float* Xs = sf;
    float* Ws = sf + TILE * XS_LD;

    const int b = blockIdx.y;
    const int o0 = blockIdx.x * TILE;
    const int tid = threadIdx.x;
    const int tx = tid & 15, ty = tid >> 4;

    double acc[4][4];
#pragma unroll
    for (int i = 0; i < 4; ++i)
#pragma unroll
        for (int j = 0; j < 4; ++j) acc[i][j] = 0.0;

    const int r = tid >> 3, c4 = (tid & 7) * 4;
    const float* xbase = x + (size_t)b * F_DIM;

    for (int k0 = 0; k0 < K_DIM; k0 += KC) {
        __syncthreads();
        float4 xv0 = *reinterpret_cast<const float4*>(xbase + (size_t)r * COLS + k0 + c4);
        float4 xv1 = *reinterpret_cast<const float4*>(xbase + (size_t)(r + 32) * COLS + k0 + c4);
        *reinterpret_cast<float4*>(Xs + r * XS_LD + c4) = xv0;
        *reinterpret_cast<float4*>(Xs + (r + 32) * XS_LD + c4) = xv1;
        float4 wv0 = *reinterpret_cast<const float4*>(Wm + (size_t)(o0 + r) * K_DIM + k0 + c4);
        float4 wv1 = *reinterpret_cast<const float4*>(Wm + (size_t)(o0 + r + 32) * K_DIM + k0 + c4);
        *reinterpret_cast<float4*>(Ws + r * XS_LD + c4) = wv0;
        *reinterpret_cast<float4*>(Ws + (r + 32) * XS_LD + c4) = wv1;
        __syncthreads();
#pragma unroll 4
        for (int kk = 0; kk < KC; ++kk) {
            double xa[4], wb[4];
#pragma unroll
            for (int i = 0; i < 4; ++i) xa[i] = (double)Xs[(4 * ty + i) * XS_LD + kk];
#pragma unroll
            for (int j = 0; j < 4; ++j) wb[j] = (double)Ws[(4 * tx + j) * XS_LD + kk];
#pragma unroll
            for (int i = 0; i < 4; ++i)
#pragma unroll
                for (int j = 0; j < 4; ++j) acc[i][j] = fma(xa[i], wb[j], acc[i][j]);
        }
    }
    __syncthreads();
#pragma unroll
    for (int i = 0; i < 4; ++i)
#pragma unroll
        for (int j = 0; j < 4; ++j) sd[(4 * ty + i) * SC_LD + (4 * tx + j)] = acc[i][j];
    __syncthreads();
    if (tid < TILE) {
        double v = 0.0;
        float* outp = out + (size_t)b * F_DIM + o0 + tid;
        for (int t = 0; t < T_DIM; ++t) {
            double cu = sd[t * SC_LD + tid];
            double h = v + (cu - v) * 0.5;
            bool s = (h >= 1.0);
            outp[(size_t)t * COLS] = s ? 1.0f : 0.0f;
            v = s ? 0.0 : h;
        }
    }
}

// ------------------------------------------------------------------- launch
extern "C" void kernel_launch(void* const* d_in, const int* in_sizes, int n_in,
                              void* d_out, int out_size, void* d_ws, size_t ws_size,
                              hipStream_t stream) {
    const float* x = (const float*)d_in[0];   // [64][256][1024]
    const float* Wm = (const float*)d_in[1];  // [1024][1024]
    float* out = (float*)d_out;

    const size_t OFF_B   = 0;                                   // 4 MB packed W
    const size_t OFF_CNT = OFF_B + (size_t)F_DIM * KP * 2;
    const size_t OFF_LST = OFF_CNT + 256;
    const size_t NEEDED  = OFF_LST + (size_t)LIST_CAP * 4;

    if (ws_size < NEEDED) {
        dim3 grid(F_DIM / TILE, B_DIM, 1);
        lif_fused_kernel<<<grid, dim3(256), 0, stream>>>(x, Wm, out);
        return;
    }

    unsigned char* ws = (unsigned char*)d_ws;
    unsigned short* Bbuf = (unsigned short*)(ws + OFF_B);
    unsigned int* counter = (unsigned int*)(ws + OFF_CNT);
    unsigned int* list = (unsigned int*)(ws + OFF_LST);

    split_w_kernel<<<dim3(512), dim3(256), 0, stream>>>(Wm, Bbuf, counter);
    gemm_scan_kernel<<<dim3(256), dim3(512), 0, stream>>>(x, Bbuf, out, counter, list);
    fixup_kernel<<<dim3(512), dim3(256), 0, stream>>>(x, Wm, counter, list, out);
}

// Round 7
// 209.285 us; speedup vs baseline: 1.1499x; 1.1499x over previous
//
#include <hip/hip_runtime.h>

// LinearLIFBlock: cur = X[16384x1024] * W^T[1024x1024]; LIF scan over t (64 steps).
// R16: R15 fused-split structure + COMPUTE register-peak fix. R15's +53 MB
// WRITE_SIZE (= 16 B/thread/k-tile scratch) came from holding 16 f32 staging
// temps across a COMPUTE whose fragment liveness peaked at 80 VGPRs
// (ah[8]+al[8] resident). R16 flips the residency: bh[4]/bl[4] resident for
// the whole tile, ah[4]/al[4] loaded per i-half -> fragment peak 64, +16 fA
// temps = 80 = R14's proven non-spilling level. Per-element product order
// (ah*bh -> al*bh -> ah*bl, same k order) unchanged -> cur bit-identical ->
// same margin-flag set. Everything else is R15 verbatim: A staged from raw
// f32 X (T14 issue-early / cvt-write-late), B via global_load_lds from packed
// 4 MB buffer (split_w), 2-phase dbuf with HARD_SYNC boundaries (R12-validated
// race discipline), 256x256 tile, wave 128x64, grid 256, XOR swizzle, LIF
// relay, margin 6e-5 + exact fp64 fixup.
// Decision criterion: WRITE ~68 MB = spill gone; WRITE >80 MB = fusion dead,
// revert to R14.

#define T_DIM 64
#define B_DIM 256
#define F_DIM 1024
#define K_DIM 1024
#define M_DIM 16384            // T*B
#define COLS  (B_DIM * F_DIM)  // 262144 scan columns
#define KP    2048             // packed K: [hi | lo]
#define MARGIN 6e-5f
#define LIST_CAP 32768

typedef __attribute__((ext_vector_type(8))) short short8;
typedef __attribute__((ext_vector_type(4))) float floatx4;

#define ASYNC_CP16(gp, lp)                                                     \
    __builtin_amdgcn_global_load_lds(                                          \
        (const __attribute__((address_space(1))) unsigned int*)(gp),           \
        (__attribute__((address_space(3))) unsigned int*)(lp), 16, 0, 0)

// Hardened pipeline sync: explicit full drain + pinned ordering (R12-validated).
#define HARD_SYNC() do {                                                       \
        __builtin_amdgcn_sched_barrier(0);                                     \
        asm volatile("s_waitcnt vmcnt(0) lgkmcnt(0)" ::: "memory");            \
        __syncthreads();                                                       \
        __builtin_amdgcn_sched_barrier(0);                                     \
    } while (0)

// ---------------------------------------------------------------- bf16 split
__device__ inline unsigned short f32_to_bf16_rne(float f) {
    unsigned int u = __builtin_bit_cast(unsigned int, f);
    unsigned int r = (u + 0x7FFFu + ((u >> 16) & 1u)) >> 16;
    return (unsigned short)r;
}
__device__ inline float bf16_to_f32(unsigned short h) {
    unsigned int u = ((unsigned int)h) << 16;
    return __builtin_bit_cast(float, u);
}

// W-only split: 512 blocks x 256 threads x 8 floats = 1M floats (whole W).
// Per-element conversion identical to R12/R14 -> bit-identical B buffer.
// Also zeroes the fixup counter (blk 0).
__global__ __launch_bounds__(256) void split_w_kernel(
    const float* __restrict__ Wm, unsigned short* __restrict__ B,
    unsigned int* __restrict__ counter)
{
    if (blockIdx.x == 0 && threadIdx.x == 0) *counter = 0;
    const int g2 = blockIdx.x * 256 + threadIdx.x;   // float8-group index
    const int e = g2 * 8;
    const int orow = e >> 10;                        // o
    const int k = e & 1023;
    float4 v0 = reinterpret_cast<const float4*>(Wm)[g2 * 2];
    float4 v1 = reinterpret_cast<const float4*>(Wm)[g2 * 2 + 1];
    float fs[8] = {v0.x, v0.y, v0.z, v0.w, v1.x, v1.y, v1.z, v1.w};
    short8 hv, lv;
#pragma unroll
    for (int i = 0; i < 8; ++i) {
        unsigned short h = f32_to_bf16_rne(fs[i]);
        unsigned short l = f32_to_bf16_rne(fs[i] - bf16_to_f32(h));
        hv[i] = (short)h;
        lv[i] = (short)l;
    }
    reinterpret_cast<short8*>(B)[(size_t)orow * (KP / 8) + (k >> 3)] = hv;
    reinterpret_cast<short8*>(B)[(size_t)orow * (KP / 8) + 128 + (k >> 3)] = lv;
}

// ----------------------------------------------- fused MFMA GEMM + LIF scan
// Block tile 256(M) x 256(N); 512 threads (8 waves, 2M x 4N), wave 128x64.
// A staged from raw f32 X (reg-staged + on-the-fly hi/lo split); B staged
// from packed buffer via global_load_lds. 2-phase dbuf, one hardened barrier
// per k-tile.  cur = A.hi*B.hi + A.lo*B.hi + A.hi*B.lo
__global__ __launch_bounds__(512, 2) void gemm_scan_kernel(
    const float* __restrict__ x,           // [64][256][1024] f32
    const unsigned short* __restrict__ B,  // [1024][2048] packed hi|lo, rows o
    float* __restrict__ out,
    unsigned int* __restrict__ counter, unsigned int* __restrict__ list)
{
    __shared__ unsigned short Ah0[256 * 32], Al0[256 * 32];  // 32 KB
    __shared__ unsigned short Bh0[256 * 32], Bl0[256 * 32];  // 32 KB
    __shared__ unsigned short Ah1[256 * 32], Al1[256 * 32];  // 32 KB
    __shared__ unsigned short Bh1[256 * 32], Bl1[256 * 32];  // 32 KB

    const int tid  = threadIdx.x;
    const int lane = tid & 63;
    const int wv   = tid >> 6;                       // 0..7
    // XCD-aware: XCD = lid&7 owns 8 mt x 4 nt contiguous blocks.
    const int lid = blockIdx.x;                      // 0..255
    const int mt  = ((lid & 7) << 3) | (lid >> 5);   // 0..63
    const int nt  = (lid >> 3) & 3;                  // 0..3
    const int m0  = mt * 256;
    const int n0  = nt * 256;
    const int wm  = (wv & 1) * 128;
    const int wn  = (wv >> 1) * 64;

    floatx4 acc[8][4] = {};

    // Staging with source-side XOR chunk swizzle (R5/R7-validated: 0 conflicts).
    const int srow = tid >> 2;                      // 0..127 staging row
    const int slin = (tid & 3) * 8;                 // linear LDS chunk (dest)
    const int ssw  = (((tid & 3) ^ ((srow >> 1) & 3)) * 8);  // swizzled source chunk
    const int lrow = lane & 15;
    const int q    = lane >> 4;                     // 0..3
    const int rsw  = (lrow >> 1) & 3;               // read-side swizzle key
    const int sl   = (q ^ rsw) * 8;

    // A source: rows of the logical packed-A matrix map back to x:
    //   A-row ar = b*64 + t  <->  x-row = t*256 + b   (b = ar>>6, t = ar&63)
    const int ar0 = m0 + srow;
    const int ar1 = ar0 + 128;
    const float* xr0 =
        x + ((size_t)(ar0 & 63) * 256 + (ar0 >> 6)) * 1024 + ssw;
    const float* xr1 =
        x + ((size_t)(ar1 & 63) * 256 + (ar1 >> 6)) * 1024 + ssw;

    // B source (packed, pre-swizzled); rows srow and srow+128
    const size_t RKP = (size_t)128 * KP;
    const unsigned short* gb_h = B + (size_t)(n0 + srow) * KP + ssw;
    const unsigned short* gb_l = gb_h + 1024;

    // LDS dest offsets (lane-linear within each wave: lane -> base + lane*16B)
    const int ldsA  = srow * 32 + slin;
    const int ldsA2 = (srow + 128) * 32 + slin;

    // fragment read offsets
    int aoff[8], boff[4];
#pragma unroll
    for (int i = 0; i < 8; ++i) aoff[i] = (wm + i * 16 + lrow) * 32 + sl;
#pragma unroll
    for (int j = 0; j < 4; ++j) boff[j] = (wn + j * 16 + lrow) * 32 + sl;

    // f32 staging temps (live across COMPUTE; die before HARD_SYNC)
    float4 fA0, fA0b, fA1, fA1b;

#define STAGE_A_LOAD(kk) do {                                                  \
        fA0  = *reinterpret_cast<const float4*>(xr0 + (kk));                   \
        fA0b = *reinterpret_cast<const float4*>(xr0 + (kk) + 4);               \
        fA1  = *reinterpret_cast<const float4*>(xr1 + (kk));                   \
        fA1b = *reinterpret_cast<const float4*>(xr1 + (kk) + 4);               \
    } while (0)

#define STAGE_B(BhB, BlB, kk) do {                                             \
        ASYNC_CP16(gb_h + (kk),       &BhB[ldsA]);                             \
        ASYNC_CP16(gb_h + RKP + (kk), &BhB[ldsA2]);                            \
        ASYNC_CP16(gb_l + (kk),       &BlB[ldsA]);                             \
        ASYNC_CP16(gb_l + RKP + (kk), &BlB[ldsA2]);                            \
    } while (0)

// Convert 8 f32 -> hi/lo bf16 short8 and store to LDS. RNE math identical to
// the split kernel -> bit-identical LDS bytes.
#define CVT8(dsth, dstl, va, vb) do {                                          \
        float fs[8] = {va.x, va.y, va.z, va.w, vb.x, vb.y, vb.z, vb.w};        \
        short8 hv, lv;                                                         \
        _Pragma("unroll")                                                      \
        for (int ii = 0; ii < 8; ++ii) {                                       \
            unsigned short h = f32_to_bf16_rne(fs[ii]);                        \
            unsigned short l = f32_to_bf16_rne(fs[ii] - bf16_to_f32(h));       \
            hv[ii] = (short)h;                                                 \
            lv[ii] = (short)l;                                                 \
        }                                                                      \
        *reinterpret_cast<short8*>(dsth) = hv;                                 \
        *reinterpret_cast<short8*>(dstl) = lv;                                 \
    } while (0)

#define CVT_WRITE(AhB, AlB) do {                                               \
        CVT8(&AhB[ldsA],  &AlB[ldsA],  fA0, fA0b);                             \
        CVT8(&AhB[ldsA2], &AlB[ldsA2], fA1, fA1b);                             \
    } while (0)

// Register-peak-capped COMPUTE: bh[4]/bl[4] resident across the tile (32
// VGPRs); ah[4]/al[4] per i-half (32) -> fragment peak 64 (R15: 80). Per-acc-
// element product order ah*bh -> al*bh -> ah*bl preserved exactly.
#define COMPUTE(AhB, AlB, BhB, BlB) do {                                       \
        short8 bh[4], bl[4];                                                   \
        _Pragma("unroll")                                                      \
        for (int j = 0; j < 4; ++j) {                                          \
            bh[j] = *reinterpret_cast<const short8*>(&BhB[boff[j]]);           \
            bl[j] = *reinterpret_cast<const short8*>(&BlB[boff[j]]);           \
        }                                                                      \
        _Pragma("unroll")                                                      \
        for (int ih = 0; ih < 2; ++ih) {                                       \
            short8 ah[4], al[4];                                               \
            _Pragma("unroll")                                                  \
            for (int i4 = 0; i4 < 4; ++i4) {                                   \
                ah[i4] = *reinterpret_cast<const short8*>(&AhB[aoff[ih * 4 + i4]]); \
                al[i4] = *reinterpret_cast<const short8*>(&AlB[aoff[ih * 4 + i4]]); \
            }                                                                  \
            __builtin_amdgcn_s_setprio(1);                                     \
            _Pragma("unroll")                                                  \
            for (int i4 = 0; i4 < 4; ++i4)                                     \
                _Pragma("unroll")                                              \
                for (int j = 0; j < 4; ++j)                                    \
                    acc[ih * 4 + i4][j] = __builtin_amdgcn_mfma_f32_16x16x32_bf16( \
                        ah[i4], bh[j], acc[ih * 4 + i4][j], 0, 0, 0);          \
            _Pragma("unroll")                                                  \
            for (int i4 = 0; i4 < 4; ++i4)                                     \
                _Pragma("unroll")                                              \
                for (int j = 0; j < 4; ++j)                                    \
                    acc[ih * 4 + i4][j] = __builtin_amdgcn_mfma_f32_16x16x32_bf16( \
                        al[i4], bh[j], acc[ih * 4 + i4][j], 0, 0, 0);          \
            _Pragma("unroll")                                                  \
            for (int i4 = 0; i4 < 4; ++i4)                                     \
                _Pragma("unroll")                                              \
                for (int j = 0; j < 4; ++j)                                    \
                    acc[ih * 4 + i4][j] = __builtin_amdgcn_mfma_f32_16x16x32_bf16( \
                        ah[i4], bl[j], acc[ih * 4 + i4][j], 0, 0, 0);          \
            __builtin_amdgcn_s_setprio(0);                                     \
        }                                                                      \
    } while (0)

    // prologue: fill buf0 for k-tile 0 (A: load -> cvt -> ds_write; B: gload_lds)
    STAGE_A_LOAD(0);
    STAGE_B(Bh0, Bl0, 0);
    CVT_WRITE(Ah0, Al0);
    HARD_SYNC();   // buf0 ready (vmcnt(0) drains B; lgkmcnt(0) drains A writes)

#pragma unroll 1
    for (int kt = 0; kt < 32; kt += 2) {
        // phase A: compute tile kt from buf0; prep tile kt+1 into buf1
        STAGE_A_LOAD((kt + 1) * 32);
        STAGE_B(Bh1, Bl1, (kt + 1) * 32);
        __builtin_amdgcn_sched_barrier(0);   // loads stay issued before MFMA
        COMPUTE(Ah0, Al0, Bh0, Bl0);
        __builtin_amdgcn_sched_barrier(0);   // cvt stays after MFMA (T14 write-late)
        CVT_WRITE(Ah1, Al1);
        HARD_SYNC();   // buf1 ready; buf0 free to overwrite
        // phase B: compute tile kt+1 from buf1; prep tile kt+2 into buf0
        if (kt + 2 < 32) {
            STAGE_A_LOAD((kt + 2) * 32);
            STAGE_B(Bh0, Bl0, (kt + 2) * 32);
        }
        __builtin_amdgcn_sched_barrier(0);
        COMPUTE(Ah1, Al1, Bh1, Bl1);
        __builtin_amdgcn_sched_barrier(0);
        if (kt + 2 < 32) CVT_WRITE(Ah0, Al0);
        HARD_SYNC();
    }

#undef STAGE_A_LOAD
#undef STAGE_B
#undef CVT8
#undef CVT_WRITE
#undef COMPUTE

    // ---- fused LIF scan in registers (validated relay, 2 batches/wave) ----
    // Wave rows wm..wm+127 = batches b_base, b_base+1 (64 t each).
    // acc[i][j][r] = cur at batch b_base+(i>>2), t = (i&3)*16 + q*4 + r,
    // col o = n0 + wn + j*16 + (lane&15).
    const int col = lane & 15;
    const int b_base = mt * 4 + (wv & 1) * 2;

    unsigned int fmask = 0;
#pragma unroll
    for (int hb = 0; hb < 2; ++hb) {
#pragma unroll
        for (int j = 0; j < 4; ++j) {
            float v = 0.f;
            bool fl = false;
#pragma unroll
            for (int i4 = 0; i4 < 4; ++i4) {
                const int i = hb * 4 + i4;
#pragma unroll
                for (int qq = 0; qq < 4; ++qq) {
                    if (q == qq) {
#pragma unroll
                        for (int r = 0; r < 4; ++r) {
                            float cu = acc[i][j][r];
                            float hm = v + (cu - v) * 0.5f;
                            float d = hm - 1.0f;
                            bool sp = (d >= 0.f);
                            fl |= (fabsf(d) < MARGIN);
                            acc[i][j][r] = sp ? 1.0f : 0.0f;  // spike overwrites cur
                            v = sp ? 0.f : hm;
                        }
                    }
                    v = __shfl(v, qq * 16 + col, 64);  // broadcast owner's v
                }
            }
            if (fl) fmask |= (1u << (hb * 4 + j));
        }
    }
    fmask |= __shfl_xor(fmask, 16, 64);
    fmask |= __shfl_xor(fmask, 32, 64);

    // spike stores
#pragma unroll
    for (int i = 0; i < 8; ++i) {
        float* outp = out + (size_t)(b_base + (i >> 2)) * F_DIM;
        const int tb = (i & 3) * 16 + q * 4;
#pragma unroll
        for (int j = 0; j < 4; ++j)
#pragma unroll
            for (int r = 0; r < 4; ++r)
                outp[(size_t)(tb + r) * COLS + (n0 + wn + j * 16 + col)] = acc[i][j][r];
    }

    if (q == 0 && fmask) {
        for (int hb = 0; hb < 2; ++hb)
            for (int j = 0; j < 4; ++j)
                if (fmask & (1u << (hb * 4 + j))) {
                    unsigned int idx = atomicAdd(counter, 1u);
                    if (idx < LIST_CAP)
                        list[idx] = (unsigned int)(((b_base + hb) << 10) |
                                                   (n0 + wn + j * 16 + col));
                }
    }
}

// ------------------------------------------------------- exact fp64 fixup
__global__ __launch_bounds__(256) void fixup_kernel(
    const float* __restrict__ x, const float* __restrict__ W,
    const unsigned int* __restrict__ counter, const unsigned int* __restrict__ list,
    float* __restrict__ out)
{
    __shared__ double curd[T_DIM];
    __shared__ float wrow[K_DIM];
    unsigned int n = *counter;
    if (n > LIST_CAP) n = LIST_CAP;
    const int wv = threadIdx.x >> 6, lane = threadIdx.x & 63;

    for (unsigned int idx = blockIdx.x; idx < n; idx += gridDim.x) {
        const unsigned int c = list[idx];
        const int b = c >> 10, o = c & 1023;
        __syncthreads();
        for (int k = threadIdx.x; k < K_DIM; k += 256) wrow[k] = W[(size_t)o * K_DIM + k];
        __syncthreads();
        for (int it = 0; it < 16; ++it) {
            const int t = it * 4 + wv;
            const float* xp = x + (size_t)t * COLS + (size_t)b * F_DIM + lane * 16;
            double s = 0.0;
#pragma unroll
            for (int qq = 0; qq < 4; ++qq) {
                float4 xv = reinterpret_cast<const float4*>(xp)[qq];
                float4 wq = *reinterpret_cast<const float4*>(&wrow[lane * 16 + qq * 4]);
                s += (double)xv.x * (double)wq.x + (double)xv.y * (double)wq.y +
                     (double)xv.z * (double)wq.z + (double)xv.w * (double)wq.w;
            }
#pragma unroll
            for (int off = 32; off > 0; off >>= 1) s += __shfl_down(s, off, 64);
            if (lane == 0) curd[t] = s;
        }
        __syncthreads();
        if (threadIdx.x == 0) {
            double v = 0.0;
            for (int t = 0; t < T_DIM; ++t) {
                double h = v + (curd[t] - v) * 0.5;
                bool s = (h >= 1.0);
                out[(size_t)t * COLS + c] = s ? 1.0f : 0.0f;
                v = s ? 0.0 : h;
            }
        }
        __syncthreads();
    }
}

// --------------------------------------------------- fp64 fallback (round-1)
#define TILE 64
#define KC 32
#define XS_LD 36
#define SC_LD 65

__global__ __launch_bounds__(256) void lif_fused_kernel(
    const float* __restrict__ x, const float* __restrict__ Wm, float* __restrict__ out)
{
    __shared__ __align__(16) unsigned char smem_raw[TILE * SC_LD * sizeof(double)];
    float* sf = reinterpret_cast<float*>(smem_raw);
    double* sd = reinterpret_cast<double*>(smem_raw);
    float* Xs = sf;
    float* Ws = sf + TILE * XS_LD;

    const int b = blockIdx.y;
    const int o0 = blockIdx.x * TILE;
    const int tid = threadIdx.x;
    const int tx = tid & 15, ty = tid >> 4;

    double acc[4][4];
#pragma unroll
    for (int i = 0; i < 4; ++i)
#pragma unroll
        for (int j = 0; j < 4; ++j) acc[i][j] = 0.0;

    const int r = tid >> 3, c4 = (tid & 7) * 4;
    const float* xbase = x + (size_t)b * F_DIM;

    for (int k0 = 0; k0 < K_DIM; k0 += KC) {
        __syncthreads();
        float4 xv0 = *reinterpret_cast<const float4*>(xbase + (size_t)r * COLS + k0 + c4);
        float4 xv1 = *reinterpret_cast<const float4*>(xbase + (size_t)(r + 32) * COLS + k0 + c4);
        *reinterpret_cast<float4*>(Xs + r * XS_LD + c4) = xv0;
        *reinterpret_cast<float4*>(Xs + (r + 32) * XS_LD + c4) = xv1;
        float4 wv0 = *reinterpret_cast<const float4*>(Wm + (size_t)(o0 + r) * K_DIM + k0 + c4);
        float4 wv1 = *reinterpret_cast<const float4*>(Wm + (size_t)(o0 + r + 32) * K_DIM + k0 + c4);
        *reinterpret_cast<float4*>(Ws + r * XS_LD + c4) = wv0;
        *reinterpret_cast<float4*>(Ws + (r + 32) * XS_LD + c4) = wv1;
        __syncthreads();
#pragma unroll 4
        for (int kk = 0; kk < KC; ++kk) {
            double xa[4], wb[4];
#pragma unroll
            for (int i = 0; i < 4; ++i) xa[i] = (double)Xs[(4 * ty + i) * XS_LD + kk];
#pragma unroll
            for (int j = 0; j < 4; ++j) wb[j] = (double)Ws[(4 * tx + j) * XS_LD + kk];
#pragma unroll
            for (int i = 0; i < 4; ++i)
#pragma unroll
                for (int j = 0; j < 4; ++j) acc[i][j] = fma(xa[i], wb[j], acc[i][j]);
        }
    }
    __syncthreads();
#pragma unroll
    for (int i = 0; i < 4; ++i)
#pragma unroll
        for (int j = 0; j < 4; ++j) sd[(4 * ty + i) * SC_LD + (4 * tx + j)] = acc[i][j];
    __syncthreads();
    if (tid < TILE) {
        double v = 0.0;
        float* outp = out + (size_t)b * F_DIM + o0 + tid;
        for (int t = 0; t < T_DIM; ++t) {
            double cu = sd[t * SC_LD + tid];
            double h = v + (cu - v) * 0.5;
            bool s = (h >= 1.0);
            outp[(size_t)t * COLS] = s ? 1.0f : 0.0f;
            v = s ? 0.0 : h;
        }
    }
}

// ------------------------------------------------------------------- launch
extern "C" void kernel_launch(void* const* d_in, const int* in_sizes, int n_in,
                              void* d_out, int out_size, void* d_ws, size_t ws_size,
                              hipStream_t stream) {
    const float* x = (const float*)d_in[0];   // [64][256][1024]
    const float* Wm = (const float*)d_in[1];  // [1024][1024]
    float* out = (float*)d_out;

    const size_t OFF_B   = 0;                                   // 4 MB packed W
    const size_t OFF_CNT = OFF_B + (size_t)F_DIM * KP * 2;
    const size_t OFF_LST = OFF_CNT + 256;
    const size_t NEEDED  = OFF_LST + (size_t)LIST_CAP * 4;

    if (ws_size < NEEDED) {
        dim3 grid(F_DIM / TILE, B_DIM, 1);
        lif_fused_kernel<<<grid, dim3(256), 0, stream>>>(x, Wm, out);
        return;
    }

    unsigned char* ws = (unsigned char*)d_ws;
    unsigned short* Bbuf = (unsigned short*)(ws + OFF_B);
    unsigned int* counter = (unsigned int*)(ws + OFF_CNT);
    unsigned int* list = (unsigned int*)(ws + OFF_LST);

    split_w_kernel<<<dim3(512), dim3(256), 0, stream>>>(Wm, Bbuf, counter);
    gemm_scan_kernel<<<dim3(256), dim3(512), 0, stream>>>(x, Bbuf, out, counter, list);
    fixup_kernel<<<dim3(512), dim3(256), 0, stream>>>(x, Wm, counter, list, out);
}

// Round 9
// 207.487 us; speedup vs baseline: 1.1599x; 1.0087x over previous
//
#include <hip/hip_runtime.h>

// LinearLIFBlock: cur = X[16384x1024] * W^T[1024x1024]; LIF scan over t (64 steps).
// R18: R17 resubmitted verbatim (R17's bench died to a container-infra
// failure; no data). Change under test vs R16: the post-COMPUTE
// sched_barrier(0) is removed, so the scheduler may interleave CVT_WRITE's
// ~100 cvt VALU ops + 4 ds_writes into MFMA issue gaps (separate pipes)
// instead of paying them serially before each HARD_SYNC (~500-600 cyc/tile).
// Register math: interleaved liveness bh/bl(32)+ah/al(32)+fA(16)+cvt(~16)
// +addr ~= 116 arch-VGPR < 128 alloc (acc in AGPRs) -> no spill expected.
// First SB(0) kept: pins B global_load_lds issue before the MFMA stream so
// the HARD_SYNC vmcnt(0) drain stays free. Sync structure (HARD_SYNC, dbuf)
// bit-identical to race-validated R12/R16. Numerics untouched -> cur
// bit-identical -> same margin-flag set. 256x256 tile, wave 128x64, grid 256,
// XOR swizzle, LIF relay, margin 6e-5 + exact fp64 fixup, split_w (4 MB).
// Decision criteria: WRITE >80 MB = scheduler spilled -> restore the pin.
// Clean at ~107 -> R19 tries counted-vmcnt phase pipeline on this template.

#define T_DIM 64
#define B_DIM 256
#define F_DIM 1024
#define K_DIM 1024
#define M_DIM 16384            // T*B
#define COLS  (B_DIM * F_DIM)  // 262144 scan columns
#define KP    2048             // packed K: [hi | lo]
#define MARGIN 6e-5f
#define LIST_CAP 32768

typedef __attribute__((ext_vector_type(8))) short short8;
typedef __attribute__((ext_vector_type(4))) float floatx4;

#define ASYNC_CP16(gp, lp)                                                     \
    __builtin_amdgcn_global_load_lds(                                          \
        (const __attribute__((address_space(1))) unsigned int*)(gp),           \
        (__attribute__((address_space(3))) unsigned int*)(lp), 16, 0, 0)

// Hardened pipeline sync: explicit full drain + pinned ordering (R12-validated).
#define HARD_SYNC() do {                                                       \
        __builtin_amdgcn_sched_barrier(0);                                     \
        asm volatile("s_waitcnt vmcnt(0) lgkmcnt(0)" ::: "memory");            \
        __syncthreads();                                                       \
        __builtin_amdgcn_sched_barrier(0);                                     \
    } while (0)

// ---------------------------------------------------------------- bf16 split
__device__ inline unsigned short f32_to_bf16_rne(float f) {
    unsigned int u = __builtin_bit_cast(unsigned int, f);
    unsigned int r = (u + 0x7FFFu + ((u >> 16) & 1u)) >> 16;
    return (unsigned short)r;
}
__device__ inline float bf16_to_f32(unsigned short h) {
    unsigned int u = ((unsigned int)h) << 16;
    return __builtin_bit_cast(float, u);
}

// W-only split: 512 blocks x 256 threads x 8 floats = 1M floats (whole W).
// Per-element conversion identical to R12/R14 -> bit-identical B buffer.
// Also zeroes the fixup counter (blk 0).
__global__ __launch_bounds__(256) void split_w_kernel(
    const float* __restrict__ Wm, unsigned short* __restrict__ B,
    unsigned int* __restrict__ counter)
{
    if (blockIdx.x == 0 && threadIdx.x == 0) *counter = 0;
    const int g2 = blockIdx.x * 256 + threadIdx.x;   // float8-group index
    const int e = g2 * 8;
    const int orow = e >> 10;                        // o
    const int k = e & 1023;
    float4 v0 = reinterpret_cast<const float4*>(Wm)[g2 * 2];
    float4 v1 = reinterpret_cast<const float4*>(Wm)[g2 * 2 + 1];
    float fs[8] = {v0.x, v0.y, v0.z, v0.w, v1.x, v1.y, v1.z, v1.w};
    short8 hv, lv;
#pragma unroll
    for (int i = 0; i < 8; ++i) {
        unsigned short h = f32_to_bf16_rne(fs[i]);
        unsigned short l = f32_to_bf16_rne(fs[i] - bf16_to_f32(h));
        hv[i] = (short)h;
        lv[i] = (short)l;
    }
    reinterpret_cast<short8*>(B)[(size_t)orow * (KP / 8) + (k >> 3)] = hv;
    reinterpret_cast<short8*>(B)[(size_t)orow * (KP / 8) + 128 + (k >> 3)] = lv;
}

// ----------------------------------------------- fused MFMA GEMM + LIF scan
// Block tile 256(M) x 256(N); 512 threads (8 waves, 2M x 4N), wave 128x64.
// A staged from raw f32 X (reg-staged + on-the-fly hi/lo split); B staged
// from packed buffer via global_load_lds. 2-phase dbuf, one hardened barrier
// per k-tile.  cur = A.hi*B.hi + A.lo*B.hi + A.hi*B.lo
__global__ __launch_bounds__(512, 2) void gemm_scan_kernel(
    const float* __restrict__ x,           // [64][256][1024] f32
    const unsigned short* __restrict__ B,  // [1024][2048] packed hi|lo, rows o
    float* __restrict__ out,
    unsigned int* __restrict__ counter, unsigned int* __restrict__ list)
{
    __shared__ unsigned short Ah0[256 * 32], Al0[256 * 32];  // 32 KB
    __shared__ unsigned short Bh0[256 * 32], Bl0[256 * 32];  // 32 KB
    __shared__ unsigned short Ah1[256 * 32], Al1[256 * 32];  // 32 KB
    __shared__ unsigned short Bh1[256 * 32], Bl1[256 * 32];  // 32 KB

    const int tid  = threadIdx.x;
    const int lane = tid & 63;
    const int wv   = tid >> 6;                       // 0..7
    // XCD-aware: XCD = lid&7 owns 8 mt x 4 nt contiguous blocks.
    const int lid = blockIdx.x;                      // 0..255
    const int mt  = ((lid & 7) << 3) | (lid >> 5);   // 0..63
    const int nt  = (lid >> 3) & 3;                  // 0..3
    const int m0  = mt * 256;
    const int n0  = nt * 256;
    const int wm  = (wv & 1) * 128;
    const int wn  = (wv >> 1) * 64;

    floatx4 acc[8][4] = {};

    // Staging with source-side XOR chunk swizzle (R5/R7-validated: 0 conflicts).
    const int srow = tid >> 2;                      // 0..127 staging row
    const int slin = (tid & 3) * 8;                 // linear LDS chunk (dest)
    const int ssw  = (((tid & 3) ^ ((srow >> 1) & 3)) * 8);  // swizzled source chunk
    const int lrow = lane & 15;
    const int q    = lane >> 4;                     // 0..3
    const int rsw  = (lrow >> 1) & 3;               // read-side swizzle key
    const int sl   = (q ^ rsw) * 8;

    // A source: rows of the logical packed-A matrix map back to x:
    //   A-row ar = b*64 + t  <->  x-row = t*256 + b   (b = ar>>6, t = ar&63)
    const int ar0 = m0 + srow;
    const int ar1 = ar0 + 128;
    const float* xr0 =
        x + ((size_t)(ar0 & 63) * 256 + (ar0 >> 6)) * 1024 + ssw;
    const float* xr1 =
        x + ((size_t)(ar1 & 63) * 256 + (ar1 >> 6)) * 1024 + ssw;

    // B source (packed, pre-swizzled); rows srow and srow+128
    const size_t RKP = (size_t)128 * KP;
    const unsigned short* gb_h = B + (size_t)(n0 + srow) * KP + ssw;
    const unsigned short* gb_l = gb_h + 1024;

    // LDS dest offsets (lane-linear within each wave: lane -> base + lane*16B)
    const int ldsA  = srow * 32 + slin;
    const int ldsA2 = (srow + 128) * 32 + slin;

    // fragment read offsets
    int aoff[8], boff[4];
#pragma unroll
    for (int i = 0; i < 8; ++i) aoff[i] = (wm + i * 16 + lrow) * 32 + sl;
#pragma unroll
    for (int j = 0; j < 4; ++j) boff[j] = (wn + j * 16 + lrow) * 32 + sl;

    // f32 staging temps (live across COMPUTE; die at CVT_WRITE before HARD_SYNC)
    float4 fA0, fA0b, fA1, fA1b;

#define STAGE_A_LOAD(kk) do {                                                  \
        fA0  = *reinterpret_cast<const float4*>(xr0 + (kk));                   \
        fA0b = *reinterpret_cast<const float4*>(xr0 + (kk) + 4);               \
        fA1  = *reinterpret_cast<const float4*>(xr1 + (kk));                   \
        fA1b = *reinterpret_cast<const float4*>(xr1 + (kk) + 4);               \
    } while (0)

#define STAGE_B(BhB, BlB, kk) do {                                             \
        ASYNC_CP16(gb_h + (kk),       &BhB[ldsA]);                             \
        ASYNC_CP16(gb_h + RKP + (kk), &BhB[ldsA2]);                            \
        ASYNC_CP16(gb_l + (kk),       &BlB[ldsA]);                             \
        ASYNC_CP16(gb_l + RKP + (kk), &BlB[ldsA2]);                            \
    } while (0)

// Convert 8 f32 -> hi/lo bf16 short8 and store to LDS. RNE math identical to
// the split kernel -> bit-identical LDS bytes.
#define CVT8(dsth, dstl, va, vb) do {                                          \
        float fs[8] = {va.x, va.y, va.z, va.w, vb.x, vb.y, vb.z, vb.w};        \
        short8 hv, lv;                                                         \
        _Pragma("unroll")                                                      \
        for (int ii = 0; ii < 8; ++ii) {                                       \
            unsigned short h = f32_to_bf16_rne(fs[ii]);                        \
            unsigned short l = f32_to_bf16_rne(fs[ii] - bf16_to_f32(h));       \
            hv[ii] = (short)h;                                                 \
            lv[ii] = (short)l;                                                 \
        }                                                                      \
        *reinterpret_cast<short8*>(dsth) = hv;                                 \
        *reinterpret_cast<short8*>(dstl) = lv;                                 \
    } while (0)

#define CVT_WRITE(AhB, AlB) do {                                               \
        CVT8(&AhB[ldsA],  &AlB[ldsA],  fA0, fA0b);                             \
        CVT8(&AhB[ldsA2], &AlB[ldsA2], fA1, fA1b);                             \
    } while (0)

// Register-peak-capped COMPUTE (R16-validated): bh[4]/bl[4] resident (32
// VGPRs); ah[4]/al[4] per i-half (32) -> fragment peak 64. Per-acc-element
// product order ah*bh -> al*bh -> ah*bl preserved exactly.
#define COMPUTE(AhB, AlB, BhB, BlB) do {                                       \
        short8 bh[4], bl[4];                                                   \
        _Pragma("unroll")                                                      \
        for (int j = 0; j < 4; ++j) {                                          \
            bh[j] = *reinterpret_cast<const short8*>(&BhB[boff[j]]);           \
            bl[j] = *reinterpret_cast<const short8*>(&BlB[boff[j]]);           \
        }                                                                      \
        _Pragma("unroll")                                                      \
        for (int ih = 0; ih < 2; ++ih) {                                       \
            short8 ah[4], al[4];                                               \
            _Pragma("unroll")                                                  \
            for (int i4 = 0; i4 < 4; ++i4) {                                   \
                ah[i4] = *reinterpret_cast<const short8*>(&AhB[aoff[ih * 4 + i4]]); \
                al[i4] = *reinterpret_cast<const short8*>(&AlB[aoff[ih * 4 + i4]]); \
            }                                                                  \
            __builtin_amdgcn_s_setprio(1);                                     \
            _Pragma("unroll")                                                  \
            for (int i4 = 0; i4 < 4; ++i4)                                     \
                _Pragma("unroll")                                              \
                for (int j = 0; j < 4; ++j)                                    \
                    acc[ih * 4 + i4][j] = __builtin_amdgcn_mfma_f32_16x16x32_bf16( \
                        ah[i4], bh[j], acc[ih * 4 + i4][j], 0, 0, 0);          \
            _Pragma("unroll")                                                  \
            for (int i4 = 0; i4 < 4; ++i4)                                     \
                _Pragma("unroll")                                              \
                for (int j = 0; j < 4; ++j)                                    \
                    acc[ih * 4 + i4][j] = __builtin_amdgcn_mfma_f32_16x16x32_bf16( \
                        al[i4], bh[j], acc[ih * 4 + i4][j], 0, 0, 0);          \
            _Pragma("unroll")                                                  \
            for (int i4 = 0; i4 < 4; ++i4)                                     \
                _Pragma("unroll")                                              \
                for (int j = 0; j < 4; ++j)                                    \
                    acc[ih * 4 + i4][j] = __builtin_amdgcn_mfma_f32_16x16x32_bf16( \
                        ah[i4], bl[j], acc[ih * 4 + i4][j], 0, 0, 0);          \
            __builtin_amdgcn_s_setprio(0);                                     \
        }                                                                      \
    } while (0)

    // prologue: fill buf0 for k-tile 0 (A: load -> cvt -> ds_write; B: gload_lds)
    STAGE_A_LOAD(0);
    STAGE_B(Bh0, Bl0, 0);
    CVT_WRITE(Ah0, Al0);
    HARD_SYNC();   // buf0 ready (vmcnt(0) drains B; lgkmcnt(0) drains A writes)

#pragma unroll 1
    for (int kt = 0; kt < 32; kt += 2) {
        // phase A: compute tile kt from buf0; prep tile kt+1 into buf1.
        // No pin between COMPUTE and CVT_WRITE: scheduler may interleave the
        // cvt VALU + ds_writes into MFMA issue gaps (change under test).
        STAGE_A_LOAD((kt + 1) * 32);
        STAGE_B(Bh1, Bl1, (kt + 1) * 32);
        __builtin_amdgcn_sched_barrier(0);   // loads stay issued before MFMA
        COMPUTE(Ah0, Al0, Bh0, Bl0);
        CVT_WRITE(Ah1, Al1);
        HARD_SYNC();   // buf1 ready; buf0 free to overwrite
        // phase B: compute tile kt+1 from buf1; prep tile kt+2 into buf0
        if (kt + 2 < 32) {
            STAGE_A_LOAD((kt + 2) * 32);
            STAGE_B(Bh0, Bl0, (kt + 2) * 32);
        }
        __builtin_amdgcn_sched_barrier(0);
        COMPUTE(Ah1, Al1, Bh1, Bl1);
        if (kt + 2 < 32) CVT_WRITE(Ah0, Al0);
        HARD_SYNC();
    }

#undef STAGE_A_LOAD
#undef STAGE_B
#undef CVT8
#undef CVT_WRITE
#undef COMPUTE

    // ---- fused LIF scan in registers (validated relay, 2 batches/wave) ----
    // Wave rows wm..wm+127 = batches b_base, b_base+1 (64 t each).
    // acc[i][j][r] = cur at batch b_base+(i>>2), t = (i&3)*16 + q*4 + r,
    // col o = n0 + wn + j*16 + (lane&15).
    const int col = lane & 15;
    const int b_base = mt * 4 + (wv & 1) * 2;

    unsigned int fmask = 0;
#pragma unroll
    for (int hb = 0; hb < 2; ++hb) {
#pragma unroll
        for (int j = 0; j < 4; ++j) {
            float v = 0.f;
            bool fl = false;
#pragma unroll
            for (int i4 = 0; i4 < 4; ++i4) {
                const int i = hb * 4 + i4;
#pragma unroll
                for (int qq = 0; qq < 4; ++qq) {
                    if (q == qq) {
#pragma unroll
                        for (int r = 0; r < 4; ++r) {
                            float cu = acc[i][j][r];
                            float hm = v + (cu - v) * 0.5f;
                            float d = hm - 1.0f;
                            bool sp = (d >= 0.f);
                            fl |= (fabsf(d) < MARGIN);
                            acc[i][j][r] = sp ? 1.0f : 0.0f;  // spike overwrites cur
                            v = sp ? 0.f : hm;
                        }
                    }
                    v = __shfl(v, qq * 16 + col, 64);  // broadcast owner's v
                }
            }
            if (fl) fmask |= (1u << (hb * 4 + j));
        }
    }
    fmask |= __shfl_xor(fmask, 16, 64);
    fmask |= __shfl_xor(fmask, 32, 64);

    // spike stores
#pragma unroll
    for (int i = 0; i < 8; ++i) {
        float* outp = out + (size_t)(b_base + (i >> 2)) * F_DIM;
        const int tb = (i & 3) * 16 + q * 4;
#pragma unroll
        for (int j = 0; j < 4; ++j)
#pragma unroll
            for (int r = 0; r < 4; ++r)
                outp[(size_t)(tb + r) * COLS + (n0 + wn + j * 16 + col)] = acc[i][j][r];
    }

    if (q == 0 && fmask) {
        for (int hb = 0; hb < 2; ++hb)
            for (int j = 0; j < 4; ++j)
                if (fmask & (1u << (hb * 4 + j))) {
                    unsigned int idx = atomicAdd(counter, 1u);
                    if (idx < LIST_CAP)
                        list[idx] = (unsigned int)(((b_base + hb) << 10) |
                                                   (n0 + wn + j * 16 + col));
                }
    }
}

// ------------------------------------------------------- exact fp64 fixup
__global__ __launch_bounds__(256) void fixup_kernel(
    const float* __restrict__ x, const float* __restrict__ W,
    const unsigned int* __restrict__ counter, const unsigned int* __restrict__ list,
    float* __restrict__ out)
{
    __shared__ double curd[T_DIM];
    __shared__ float wrow[K_DIM];
    unsigned int n = *counter;
    if (n > LIST_CAP) n = LIST_CAP;
    const int wv = threadIdx.x >> 6, lane = threadIdx.x & 63;

    for (unsigned int idx = blockIdx.x; idx < n; idx += gridDim.x) {
        const unsigned int c = list[idx];
        const int b = c >> 10, o = c & 1023;
        __syncthreads();
        for (int k = threadIdx.x; k < K_DIM; k += 256) wrow[k] = W[(size_t)o * K_DIM + k];
        __syncthreads();
        for (int it = 0; it < 16; ++it) {
            const int t = it * 4 + wv;
            const float* xp = x + (size_t)t * COLS + (size_t)b * F_DIM + lane * 16;
            double s = 0.0;
#pragma unroll
            for (int qq = 0; qq < 4; ++qq) {
                float4 xv = reinterpret_cast<const float4*>(xp)[qq];
                float4 wq = *reinterpret_cast<const float4*>(&wrow[lane * 16 + qq * 4]);
                s += (double)xv.x * (double)wq.x + (double)xv.y * (double)wq.y +
                     (double)xv.z * (double)wq.z + (double)xv.w * (double)wq.w;
            }
#pragma unroll
            for (int off = 32; off > 0; off >>= 1) s += __shfl_down(s, off, 64);
            if (lane == 0) curd[t] = s;
        }
        __syncthreads();
        if (threadIdx.x == 0) {
            double v = 0.0;
            for (int t = 0; t < T_DIM; ++t) {
                double h = v + (curd[t] - v) * 0.5;
                bool s = (h >= 1.0);
                out[(size_t)t * COLS + c] = s ? 1.0f : 0.0f;
                v = s ? 0.0 : h;
            }
        }
        __syncthreads();
    }
}

// --------------------------------------------------- fp64 fallback (round-1)
#define TILE 64
#define KC 32
#define XS_LD 36
#define SC_LD 65

__global__ __launch_bounds__(256) void lif_fused_kernel(
    const float* __restrict__ x, const float* __restrict__ Wm, float* __restrict__ out)
{
    __shared__ __align__(16) unsigned char smem_raw[TILE * SC_LD * sizeof(double)];
    float* sf = reinterpret_cast<float*>(smem_raw);
    double* sd = reinterpret_cast<double*>(smem_raw);
    float* Xs = sf;
    float* Ws = sf + TILE * XS_LD;

    const int b = blockIdx.y;
    const int o0 = blockIdx.x * TILE;
    const int tid = threadIdx.x;
    const int tx = tid & 15, ty = tid >> 4;

    double acc[4][4];
#pragma unroll
    for (int i = 0; i < 4; ++i)
#pragma unroll
        for (int j = 0; j < 4; ++j) acc[i][j] = 0.0;

    const int r = tid >> 3, c4 = (tid & 7) * 4;
    const float* xbase = x + (size_t)b * F_DIM;

    for (int k0 = 0; k0 < K_DIM; k0 += KC) {
        __syncthreads();
        float4 xv0 = *reinterpret_cast<const float4*>(xbase + (size_t)r * COLS + k0 + c4);
        float4 xv1 = *reinterpret_cast<const float4*>(xbase + (size_t)(r + 32) * COLS + k0 + c4);
        *reinterpret_cast<float4*>(Xs + r * XS_LD + c4) = xv0;
        *reinterpret_cast<float4*>(Xs + (r + 32) * XS_LD + c4) = xv1;
        float4 wv0 = *reinterpret_cast<const float4*>(Wm + (size_t)(o0 + r) * K_DIM + k0 + c4);
        float4 wv1 = *reinterpret_cast<const float4*>(Wm + (size_t)(o0 + r + 32) * K_DIM + k0 + c4);
        *reinterpret_cast<float4*>(Ws + r * XS_LD + c4) = wv0;
        *reinterpret_cast<float4*>(Ws + (r + 32) * XS_LD + c4) = wv1;
        __syncthreads();
#pragma unroll 4
        for (int kk = 0; kk < KC; ++kk) {
            double xa[4], wb[4];
#pragma unroll
            for (int i = 0; i < 4; ++i) xa[i] = (double)Xs[(4 * ty + i) * XS_LD + kk];
#pragma unroll
            for (int j = 0; j < 4; ++j) wb[j] = (double)Ws[(4 * tx + j) * XS_LD + kk];
#pragma unroll
            for (int i = 0; i < 4; ++i)
#pragma unroll
                for (int j = 0; j < 4; ++j) acc[i][j] = fma(xa[i], wb[j], acc[i][j]);
        }
    }
    __syncthreads();
#pragma unroll
    for (int i = 0; i < 4; ++i)
#pragma unroll
        for (int j = 0; j < 4; ++j) sd[(4 * ty + i) * SC_LD + (4 * tx + j)] = acc[i][j];
    __syncthreads();
    if (tid < TILE) {
        double v = 0.0;
        float* outp = out + (size_t)b * F_DIM + o0 + tid;
        for (int t = 0; t < T_DIM; ++t) {
            double cu = sd[t * SC_LD + tid];
            double h = v + (cu - v) * 0.5;
            bool s = (h >= 1.0);
            outp[(size_t)t * COLS] = s ? 1.0f : 0.0f;
            v = s ? 0.0 : h;
        }
    }
}

// ------------------------------------------------------------------- launch
extern "C" void kernel_launch(void* const* d_in, const int* in_sizes, int n_in,
                              void* d_out, int out_size, void* d_ws, size_t ws_size,
                              hipStream_t stream) {
    const float* x = (const float*)d_in[0];   // [64][256][1024]
    const float* Wm = (const float*)d_in[1];  // [1024][1024]
    float* out = (float*)d_out;

    const size_t OFF_B   = 0;                                   // 4 MB packed W
    const size_t OFF_CNT = OFF_B + (size_t)F_DIM * KP * 2;
    const size_t OFF_LST = OFF_CNT + 256;
    const size_t NEEDED  = OFF_LST + (size_t)LIST_CAP * 4;

    if (ws_size < NEEDED) {
        dim3 grid(F_DIM / TILE, B_DIM, 1);
        lif_fused_kernel<<<grid, dim3(256), 0, stream>>>(x, Wm, out);
        return;
    }

    unsigned char* ws = (unsigned char*)d_ws;
    unsigned short* Bbuf = (unsigned short*)(ws + OFF_B);
    unsigned int* counter = (unsigned int*)(ws + OFF_CNT);
    unsigned int* list = (unsigned int*)(ws + OFF_LST);

    split_w_kernel<<<dim3(512), dim3(256), 0, stream>>>(Wm, Bbuf, counter);
    gemm_scan_kernel<<<dim3(256), dim3(512), 0, stream>>>(x, Bbuf, out, counter, list);
    fixup_kernel<<<dim3(512), dim3(256), 0, stream>>>(x, Wm, counter, list, out);
}

// Round 10
// 205.898 us; speedup vs baseline: 1.1688x; 1.0077x over previous
//
#include <hip/hip_runtime.h>
#include <hip/hip_bf16.h>

// LinearLIFBlock: cur = X[16384x1024] * W^T[1024x1024]; LIF scan over t (64 steps).
// R19: native bf16 conversion in the fused A-split. The manual RNE sequence
// (~5-6 VALU/element, ~200 VALU/thread/tile) is opaque bit math; plain
// __float2bfloat16 casts let the compiler emit v_cvt_pk_bf16_f32 (RNE, m240:
// casts-not-asm is the fast path), cutting cvt VALU ~4x. Numerics: RNE either
// way, finite inputs, residual sub exact -> split-error bound behind
// MARGIN=6e-5 unchanged; margin columns still get exact fp64 fixup.
// R18 post-mortem: its rocprof session was throttled (hbm 285-683 GB/s vs
// R16's 1070; profiled gemm 181 us is inconsistent with wall 207.5 = best);
// unpinned CVT_WRITE kept (WRITE ~70 MB = no spill). Register ceiling note:
// acc[8][4]=128 AGPRs + unified file + 2 waves/SIMD cap (256) leaves exactly
// 128 arch VGPRs -> deep pipelining in this geometry spills by construction
// (explains R13/R15); VALU-term reduction is the remaining cheap lever.
// Everything else R18-verbatim: A reg-staged from raw f32 X (issue-early,
// cvt-late, no post-COMPUTE pin), B via global_load_lds from packed 4 MB
// split_w buffer, 2-phase dbuf + HARD_SYNC (race-validated), 256x256 tile,
// wave 128x64, grid 256, XOR swizzle, LIF relay, margin + fp64 fixup.

#define T_DIM 64
#define B_DIM 256
#define F_DIM 1024
#define K_DIM 1024
#define M_DIM 16384            // T*B
#define COLS  (B_DIM * F_DIM)  // 262144 scan columns
#define KP    2048             // packed K: [hi | lo]
#define MARGIN 6e-5f
#define LIST_CAP 32768

typedef __attribute__((ext_vector_type(8))) short short8;
typedef __attribute__((ext_vector_type(4))) float floatx4;

#define ASYNC_CP16(gp, lp)                                                     \
    __builtin_amdgcn_global_load_lds(                                          \
        (const __attribute__((address_space(1))) unsigned int*)(gp),           \
        (__attribute__((address_space(3))) unsigned int*)(lp), 16, 0, 0)

// Hardened pipeline sync: explicit full drain + pinned ordering (R12-validated).
#define HARD_SYNC() do {                                                       \
        __builtin_amdgcn_sched_barrier(0);                                     \
        asm volatile("s_waitcnt vmcnt(0) lgkmcnt(0)" ::: "memory");            \
        __syncthreads();                                                       \
        __builtin_amdgcn_sched_barrier(0);                                     \
    } while (0)

// ---------------------------------------------------------------- bf16 split
// Manual RNE (split_w / reference path — unchanged, keeps B bit-identical).
__device__ inline unsigned short f32_to_bf16_rne(float f) {
    unsigned int u = __builtin_bit_cast(unsigned int, f);
    unsigned int r = (u + 0x7FFFu + ((u >> 16) & 1u)) >> 16;
    return (unsigned short)r;
}
__device__ inline float bf16_to_f32(unsigned short h) {
    unsigned int u = ((unsigned int)h) << 16;
    return __builtin_bit_cast(float, u);
}
// Native RNE cast (A-split in gemm): compiler emits v_cvt_pk_bf16_f32.
__device__ inline unsigned short f32_to_bf16_fast(float f) {
    __hip_bfloat16 h = __float2bfloat16(f);
    return __builtin_bit_cast(unsigned short, h);
}

// W-only split: 512 blocks x 256 threads x 8 floats = 1M floats (whole W).
// Also zeroes the fixup counter (blk 0).
__global__ __launch_bounds__(256) void split_w_kernel(
    const float* __restrict__ Wm, unsigned short* __restrict__ B,
    unsigned int* __restrict__ counter)
{
    if (blockIdx.x == 0 && threadIdx.x == 0) *counter = 0;
    const int g2 = blockIdx.x * 256 + threadIdx.x;   // float8-group index
    const int e = g2 * 8;
    const int orow = e >> 10;                        // o
    const int k = e & 1023;
    float4 v0 = reinterpret_cast<const float4*>(Wm)[g2 * 2];
    float4 v1 = reinterpret_cast<const float4*>(Wm)[g2 * 2 + 1];
    float fs[8] = {v0.x, v0.y, v0.z, v0.w, v1.x, v1.y, v1.z, v1.w};
    short8 hv, lv;
#pragma unroll
    for (int i = 0; i < 8; ++i) {
        unsigned short h = f32_to_bf16_rne(fs[i]);
        unsigned short l = f32_to_bf16_rne(fs[i] - bf16_to_f32(h));
        hv[i] = (short)h;
        lv[i] = (short)l;
    }
    reinterpret_cast<short8*>(B)[(size_t)orow * (KP / 8) + (k >> 3)] = hv;
    reinterpret_cast<short8*>(B)[(size_t)orow * (KP / 8) + 128 + (k >> 3)] = lv;
}

// ----------------------------------------------- fused MFMA GEMM + LIF scan
// Block tile 256(M) x 256(N); 512 threads (8 waves, 2M x 4N), wave 128x64.
// A staged from raw f32 X (reg-staged + on-the-fly hi/lo split); B staged
// from packed buffer via global_load_lds. 2-phase dbuf, one hardened barrier
// per k-tile.  cur = A.hi*B.hi + A.lo*B.hi + A.hi*B.lo
__global__ __launch_bounds__(512, 2) void gemm_scan_kernel(
    const float* __restrict__ x,           // [64][256][1024] f32
    const unsigned short* __restrict__ B,  // [1024][2048] packed hi|lo, rows o
    float* __restrict__ out,
    unsigned int* __restrict__ counter, unsigned int* __restrict__ list)
{
    __shared__ unsigned short Ah0[256 * 32], Al0[256 * 32];  // 32 KB
    __shared__ unsigned short Bh0[256 * 32], Bl0[256 * 32];  // 32 KB
    __shared__ unsigned short Ah1[256 * 32], Al1[256 * 32];  // 32 KB
    __shared__ unsigned short Bh1[256 * 32], Bl1[256 * 32];  // 32 KB

    const int tid  = threadIdx.x;
    const int lane = tid & 63;
    const int wv   = tid >> 6;                       // 0..7
    // XCD-aware: XCD = lid&7 owns 8 mt x 4 nt contiguous blocks.
    const int lid = blockIdx.x;                      // 0..255
    const int mt  = ((lid & 7) << 3) | (lid >> 5);   // 0..63
    const int nt  = (lid >> 3) & 3;                  // 0..3
    const int m0  = mt * 256;
    const int n0  = nt * 256;
    const int wm  = (wv & 1) * 128;
    const int wn  = (wv >> 1) * 64;

    floatx4 acc[8][4] = {};

    // Staging with source-side XOR chunk swizzle (R5/R7-validated: 0 conflicts).
    const int srow = tid >> 2;                      // 0..127 staging row
    const int slin = (tid & 3) * 8;                 // linear LDS chunk (dest)
    const int ssw  = (((tid & 3) ^ ((srow >> 1) & 3)) * 8);  // swizzled source chunk
    const int lrow = lane & 15;
    const int q    = lane >> 4;                     // 0..3
    const int rsw  = (lrow >> 1) & 3;               // read-side swizzle key
    const int sl   = (q ^ rsw) * 8;

    // A source: rows of the logical packed-A matrix map back to x:
    //   A-row ar = b*64 + t  <->  x-row = t*256 + b   (b = ar>>6, t = ar&63)
    const int ar0 = m0 + srow;
    const int ar1 = ar0 + 128;
    const float* xr0 =
        x + ((size_t)(ar0 & 63) * 256 + (ar0 >> 6)) * 1024 + ssw;
    const float* xr1 =
        x + ((size_t)(ar1 & 63) * 256 + (ar1 >> 6)) * 1024 + ssw;

    // B source (packed, pre-swizzled); rows srow and srow+128
    const size_t RKP = (size_t)128 * KP;
    const unsigned short* gb_h = B + (size_t)(n0 + srow) * KP + ssw;
    const unsigned short* gb_l = gb_h + 1024;

    // LDS dest offsets (lane-linear within each wave: lane -> base + lane*16B)
    const int ldsA  = srow * 32 + slin;
    const int ldsA2 = (srow + 128) * 32 + slin;

    // fragment read offsets
    int aoff[8], boff[4];
#pragma unroll
    for (int i = 0; i < 8; ++i) aoff[i] = (wm + i * 16 + lrow) * 32 + sl;
#pragma unroll
    for (int j = 0; j < 4; ++j) boff[j] = (wn + j * 16 + lrow) * 32 + sl;

    // f32 staging temps (live across COMPUTE; die at CVT_WRITE before HARD_SYNC)
    float4 fA0, fA0b, fA1, fA1b;

#define STAGE_A_LOAD(kk) do {                                                  \
        fA0  = *reinterpret_cast<const float4*>(xr0 + (kk));                   \
        fA0b = *reinterpret_cast<const float4*>(xr0 + (kk) + 4);               \
        fA1  = *reinterpret_cast<const float4*>(xr1 + (kk));                   \
        fA1b = *reinterpret_cast<const float4*>(xr1 + (kk) + 4);               \
    } while (0)

#define STAGE_B(BhB, BlB, kk) do {                                             \
        ASYNC_CP16(gb_h + (kk),       &BhB[ldsA]);                             \
        ASYNC_CP16(gb_h + RKP + (kk), &BhB[ldsA2]);                            \
        ASYNC_CP16(gb_l + (kk),       &BlB[ldsA]);                             \
        ASYNC_CP16(gb_l + RKP + (kk), &BlB[ldsA2]);                            \
    } while (0)

// Convert 8 f32 -> hi/lo bf16 short8 and store to LDS. Native RNE casts
// (v_cvt_pk_bf16_f32); residual lo = RNE(f - hi) with exact FP subtract.
#define CVT8(dsth, dstl, va, vb) do {                                          \
        float fs[8] = {va.x, va.y, va.z, va.w, vb.x, vb.y, vb.z, vb.w};        \
        short8 hv, lv;                                                         \
        _Pragma("unroll")                                                      \
        for (int ii = 0; ii < 8; ++ii) {                                       \
            unsigned short h = f32_to_bf16_fast(fs[ii]);                       \
            unsigned short l = f32_to_bf16_fast(fs[ii] - bf16_to_f32(h));      \
            hv[ii] = (short)h;                                                 \
            lv[ii] = (short)l;                                                 \
        }                                                                      \
        *reinterpret_cast<short8*>(dsth) = hv;                                 \
        *reinterpret_cast<short8*>(dstl) = lv;                                 \
    } while (0)

#define CVT_WRITE(AhB, AlB) do {                                               \
        CVT8(&AhB[ldsA],  &AlB[ldsA],  fA0, fA0b);                             \
        CVT8(&AhB[ldsA2], &AlB[ldsA2], fA1, fA1b);                             \
    } while (0)

// Register-peak-capped COMPUTE (R16-validated): bh[4]/bl[4] resident (32
// VGPRs); ah[4]/al[4] per i-half (32) -> fragment peak 64. Per-acc-element
// product order ah*bh -> al*bh -> ah*bl preserved exactly.
#define COMPUTE(AhB, AlB, BhB, BlB) do {                                       \
        short8 bh[4], bl[4];                                                   \
        _Pragma("unroll")                                                      \
        for (int j = 0; j < 4; ++j) {                                          \
            bh[j] = *reinterpret_cast<const short8*>(&BhB[boff[j]]);           \
            bl[j] = *reinterpret_cast<const short8*>(&BlB[boff[j]]);           \
        }                                                                      \
        _Pragma("unroll")                                                      \
        for (int ih = 0; ih < 2; ++ih) {                                       \
            short8 ah[4], al[4];                                               \
            _Pragma("unroll")                                                  \
            for (int i4 = 0; i4 < 4; ++i4) {                                   \
                ah[i4] = *reinterpret_cast<const short8*>(&AhB[aoff[ih * 4 + i4]]); \
                al[i4] = *reinterpret_cast<const short8*>(&AlB[aoff[ih * 4 + i4]]); \
            }                                                                  \
            __builtin_amdgcn_s_setprio(1);                                     \
            _Pragma("unroll")                                                  \
            for (int i4 = 0; i4 < 4; ++i4)                                     \
                _Pragma("unroll")                                              \
                for (int j = 0; j < 4; ++j)                                    \
                    acc[ih * 4 + i4][j] = __builtin_amdgcn_mfma_f32_16x16x32_bf16( \
                        ah[i4], bh[j], acc[ih * 4 + i4][j], 0, 0, 0);          \
            _Pragma("unroll")                                                  \
            for (int i4 = 0; i4 < 4; ++i4)                                     \
                _Pragma("unroll")                                              \
                for (int j = 0; j < 4; ++j)                                    \
                    acc[ih * 4 + i4][j] = __builtin_amdgcn_mfma_f32_16x16x32_bf16( \
                        al[i4], bh[j], acc[ih * 4 + i4][j], 0, 0, 0);          \
            _Pragma("unroll")                                                  \
            for (int i4 = 0; i4 < 4; ++i4)                                     \
                _Pragma("unroll")                                              \
                for (int j = 0; j < 4; ++j)                                    \
                    acc[ih * 4 + i4][j] = __builtin_amdgcn_mfma_f32_16x16x32_bf16( \
                        ah[i4], bl[j], acc[ih * 4 + i4][j], 0, 0, 0);          \
            __builtin_amdgcn_s_setprio(0);                                     \
        }                                                                      \
    } while (0)

    // prologue: fill buf0 for k-tile 0 (A: load -> cvt -> ds_write; B: gload_lds)
    STAGE_A_LOAD(0);
    STAGE_B(Bh0, Bl0, 0);
    CVT_WRITE(Ah0, Al0);
    HARD_SYNC();   // buf0 ready (vmcnt(0) drains B; lgkmcnt(0) drains A writes)

#pragma unroll 1
    for (int kt = 0; kt < 32; kt += 2) {
        // phase A: compute tile kt from buf0; prep tile kt+1 into buf1.
        // No pin between COMPUTE and CVT_WRITE: scheduler may interleave the
        // cvt VALU + ds_writes into MFMA issue gaps.
        STAGE_A_LOAD((kt + 1) * 32);
        STAGE_B(Bh1, Bl1, (kt + 1) * 32);
        __builtin_amdgcn_sched_barrier(0);   // loads stay issued before MFMA
        COMPUTE(Ah0, Al0, Bh0, Bl0);
        CVT_WRITE(Ah1, Al1);
        HARD_SYNC();   // buf1 ready; buf0 free to overwrite
        // phase B: compute tile kt+1 from buf1; prep tile kt+2 into buf0
        if (kt + 2 < 32) {
            STAGE_A_LOAD((kt + 2) * 32);
            STAGE_B(Bh0, Bl0, (kt + 2) * 32);
        }
        __builtin_amdgcn_sched_barrier(0);
        COMPUTE(Ah1, Al1, Bh1, Bl1);
        if (kt + 2 < 32) CVT_WRITE(Ah0, Al0);
        HARD_SYNC();
    }

#undef STAGE_A_LOAD
#undef STAGE_B
#undef CVT8
#undef CVT_WRITE
#undef COMPUTE

    // ---- fused LIF scan in registers (validated relay, 2 batches/wave) ----
    // Wave rows wm..wm+127 = batches b_base, b_base+1 (64 t each).
    // acc[i][j][r] = cur at batch b_base+(i>>2), t = (i&3)*16 + q*4 + r,
    // col o = n0 + wn + j*16 + (lane&15).
    const int col = lane & 15;
    const int b_base = mt * 4 + (wv & 1) * 2;

    unsigned int fmask = 0;
#pragma unroll
    for (int hb = 0; hb < 2; ++hb) {
#pragma unroll
        for (int j = 0; j < 4; ++j) {
            float v = 0.f;
            bool fl = false;
#pragma unroll
            for (int i4 = 0; i4 < 4; ++i4) {
                const int i = hb * 4 + i4;
#pragma unroll
                for (int qq = 0; qq < 4; ++qq) {
                    if (q == qq) {
#pragma unroll
                        for (int r = 0; r < 4; ++r) {
                            float cu = acc[i][j][r];
                            float hm = v + (cu - v) * 0.5f;
                            float d = hm - 1.0f;
                            bool sp = (d >= 0.f);
                            fl |= (fabsf(d) < MARGIN);
                            acc[i][j][r] = sp ? 1.0f : 0.0f;  // spike overwrites cur
                            v = sp ? 0.f : hm;
                        }
                    }
                    v = __shfl(v, qq * 16 + col, 64);  // broadcast owner's v
                }
            }
            if (fl) fmask |= (1u << (hb * 4 + j));
        }
    }
    fmask |= __shfl_xor(fmask, 16, 64);
    fmask |= __shfl_xor(fmask, 32, 64);

    // spike stores
#pragma unroll
    for (int i = 0; i < 8; ++i) {
        float* outp = out + (size_t)(b_base + (i >> 2)) * F_DIM;
        const int tb = (i & 3) * 16 + q * 4;
#pragma unroll
        for (int j = 0; j < 4; ++j)
#pragma unroll
            for (int r = 0; r < 4; ++r)
                outp[(size_t)(tb + r) * COLS + (n0 + wn + j * 16 + col)] = acc[i][j][r];
    }

    if (q == 0 && fmask) {
        for (int hb = 0; hb < 2; ++hb)
            for (int j = 0; j < 4; ++j)
                if (fmask & (1u << (hb * 4 + j))) {
                    unsigned int idx = atomicAdd(counter, 1u);
                    if (idx < LIST_CAP)
                        list[idx] = (unsigned int)(((b_base + hb) << 10) |
                                                   (n0 + wn + j * 16 + col));
                }
    }
}

// ------------------------------------------------------- exact fp64 fixup
__global__ __launch_bounds__(256) void fixup_kernel(
    const float* __restrict__ x, const float* __restrict__ W,
    const unsigned int* __restrict__ counter, const unsigned int* __restrict__ list,
    float* __restrict__ out)
{
    __shared__ double curd[T_DIM];
    __shared__ float wrow[K_DIM];
    unsigned int n = *counter;
    if (n > LIST_CAP) n = LIST_CAP;
    const int wv = threadIdx.x >> 6, lane = threadIdx.x & 63;

    for (unsigned int idx = blockIdx.x; idx < n; idx += gridDim.x) {
        const unsigned int c = list[idx];
        const int b = c >> 10, o = c & 1023;
        __syncthreads();
        for (int k = threadIdx.x; k < K_DIM; k += 256) wrow[k] = W[(size_t)o * K_DIM + k];
        __syncthreads();
        for (int it = 0; it < 16; ++it) {
            const int t = it * 4 + wv;
            const float* xp = x + (size_t)t * COLS + (size_t)b * F_DIM + lane * 16;
            double s = 0.0;
#pragma unroll
            for (int qq = 0; qq < 4; ++qq) {
                float4 xv = reinterpret_cast<const float4*>(xp)[qq];
                float4 wq = *reinterpret_cast<const float4*>(&wrow[lane * 16 + qq * 4]);
                s += (double)xv.x * (double)wq.x + (double)xv.y * (double)wq.y +
                     (double)xv.z * (double)wq.z + (double)xv.w * (double)wq.w;
            }
#pragma unroll
            for (int off = 32; off > 0; off >>= 1) s += __shfl_down(s, off, 64);
            if (lane == 0) curd[t] = s;
        }
        __syncthreads();
        if (threadIdx.x == 0) {
            double v = 0.0;
            for (int t = 0; t < T_DIM; ++t) {
                double h = v + (curd[t] - v) * 0.5;
                bool s = (h >= 1.0);
                out[(size_t)t * COLS + c] = s ? 1.0f : 0.0f;
                v = s ? 0.0 : h;
            }
        }
        __syncthreads();
    }
}

// --------------------------------------------------- fp64 fallback (round-1)
#define TILE 64
#define KC 32
#define XS_LD 36
#define SC_LD 65

__global__ __launch_bounds__(256) void lif_fused_kernel(
    const float* __restrict__ x, const float* __restrict__ Wm, float* __restrict__ out)
{
    __shared__ __align__(16) unsigned char smem_raw[TILE * SC_LD * sizeof(double)];
    float* sf = reinterpret_cast<float*>(smem_raw);
    double* sd = reinterpret_cast<double*>(smem_raw);
    float* Xs = sf;
    float* Ws = sf + TILE * XS_LD;

    const int b = blockIdx.y;
    const int o0 = blockIdx.x * TILE;
    const int tid = threadIdx.x;
    const int tx = tid & 15, ty = tid >> 4;

    double acc[4][4];
#pragma unroll
    for (int i = 0; i < 4; ++i)
#pragma unroll
        for (int j = 0; j < 4; ++j) acc[i][j] = 0.0;

    const int r = tid >> 3, c4 = (tid & 7) * 4;
    const float* xbase = x + (size_t)b * F_DIM;

    for (int k0 = 0; k0 < K_DIM; k0 += KC) {
        __syncthreads();
        float4 xv0 = *reinterpret_cast<const float4*>(xbase + (size_t)r * COLS + k0 + c4);
        float4 xv1 = *reinterpret_cast<const float4*>(xbase + (size_t)(r + 32) * COLS + k0 + c4);
        *reinterpret_cast<float4*>(Xs + r * XS_LD + c4) = xv0;
        *reinterpret_cast<float4*>(Xs + (r + 32) * XS_LD + c4) = xv1;
        float4 wv0 = *reinterpret_cast<const float4*>(Wm + (size_t)(o0 + r) * K_DIM + k0 + c4);
        float4 wv1 = *reinterpret_cast<const float4*>(Wm + (size_t)(o0 + r + 32) * K_DIM + k0 + c4);
        *reinterpret_cast<float4*>(Ws + r * XS_LD + c4) = wv0;
        *reinterpret_cast<float4*>(Ws + (r + 32) * XS_LD + c4) = wv1;
        __syncthreads();
#pragma unroll 4
        for (int kk = 0; kk < KC; ++kk) {
            double xa[4], wb[4];
#pragma unroll
            for (int i = 0; i < 4; ++i) xa[i] = (double)Xs[(4 * ty + i) * XS_LD + kk];
#pragma unroll
            for (int j = 0; j < 4; ++j) wb[j] = (double)Ws[(4 * tx + j) * XS_LD + kk];
#pragma unroll
            for (int i = 0; i < 4; ++i)
#pragma unroll
                for (int j = 0; j < 4; ++j) acc[i][j] = fma(xa[i], wb[j], acc[i][j]);
        }
    }
    __syncthreads();
#pragma unroll
    for (int i = 0; i < 4; ++i)
#pragma unroll
        for (int j = 0; j < 4; ++j) sd[(4 * ty + i) * SC_LD + (4 * tx + j)] = acc[i][j];
    __syncthreads();
    if (tid < TILE) {
        double v = 0.0;
        float* outp = out + (size_t)b * F_DIM + o0 + tid;
        for (int t = 0; t < T_DIM; ++t) {
            double cu = sd[t * SC_LD + tid];
            double h = v + (cu - v) * 0.5;
            bool s = (h >= 1.0);
            outp[(size_t)t * COLS] = s ? 1.0f : 0.0f;
            v = s ? 0.0 : h;
        }
    }
}

// ------------------------------------------------------------------- launch
extern "C" void kernel_launch(void* const* d_in, const int* in_sizes, int n_in,
                              void* d_out, int out_size, void* d_ws, size_t ws_size,
                              hipStream_t stream) {
    const float* x = (const float*)d_in[0];   // [64][256][1024]
    const float* Wm = (const float*)d_in[1];  // [1024][1024]
    float* out = (float*)d_out;

    const size_t OFF_B   = 0;                                   // 4 MB packed W
    const size_t OFF_CNT = OFF_B + (size_t)F_DIM * KP * 2;
    const size_t OFF_LST = OFF_CNT + 256;
    const size_t NEEDED  = OFF_LST + (size_t)LIST_CAP * 4;

    if (ws_size < NEEDED) {
        dim3 grid(F_DIM / TILE, B_DIM, 1);
        lif_fused_kernel<<<grid, dim3(256), 0, stream>>>(x, Wm, out);
        return;
    }

    unsigned char* ws = (unsigned char*)d_ws;
    unsigned short* Bbuf = (unsigned short*)(ws + OFF_B);
    unsigned int* counter = (unsigned int*)(ws + OFF_CNT);
    unsigned int* list = (unsigned int*)(ws + OFF_LST);

    split_w_kernel<<<dim3(512), dim3(256), 0, stream>>>(Wm, Bbuf, counter);
    gemm_scan_kernel<<<dim3(256), dim3(512), 0, stream>>>(x, Bbuf, out, counter, list);
    fixup_kernel<<<dim3(512), dim3(256), 0, stream>>>(x, Wm, counter, list, out);
}